// Round 12
// baseline (126.040 us; speedup 1.0000x reference)
//
#include <hip/hip_runtime.h>
#include <cstdint>
#include <math.h>

typedef __attribute__((ext_vector_type(8))) short short8;
typedef __attribute__((ext_vector_type(4))) float f32x4;

#define LOG2E 1.44269504088896340736f

static __device__ __forceinline__ float bf2f(unsigned short u) {
    union { unsigned int i; float f; } v; v.i = ((unsigned int)u) << 16; return v.f;
}
static __device__ __forceinline__ unsigned short f2bf(float f) {
    union { float f; unsigned int i; } v; v.f = f;
    unsigned int r = v.i + 0x7FFF + ((v.i >> 16) & 1);
    return (unsigned short)(r >> 16);
}

// ---------------- K1: fp32 -> bf16 convert (x, Wq, Wk, Wv, Wo) ----------------
__global__ __launch_bounds__(256) void k_convert(
    const float* __restrict__ x, const float* __restrict__ wq,
    const float* __restrict__ wk, const float* __restrict__ wv,
    const float* __restrict__ wo, unsigned short* __restrict__ dst) {
    long t = (long)blockIdx.x * 256 + threadIdx.x;
    long base = t * 4;
    const long NX = 2097152, NW = 1048576;
    const float* src; long off;
    if (base < NX)            { src = x;  off = base; }
    else if (base < NX + NW)  { src = wq; off = base - NX; }
    else if (base < NX + 2*NW){ src = wk; off = base - NX - NW; }
    else if (base < NX + 3*NW){ src = wv; off = base - NX - 2*NW; }
    else                      { src = wo; off = base - NX - 3*NW; }
    float4 v = *(const float4*)(src + off);
    ushort4 o;
    o.x = f2bf(v.x); o.y = f2bf(v.y); o.z = f2bf(v.z); o.w = f2bf(v.w);
    *(ushort4*)(dst + base) = o;
}

// ---------------- K2: bias materialization, compact grid + dual-h float2 ------
// (unchanged from round 9 — validated)
__global__ __launch_bounds__(256) void k_bias(
    const float* __restrict__ Eidx, const float* __restrict__ Ebar,
    const float* __restrict__ Epos, const float* __restrict__ Eoct,
    const float* __restrict__ Esemi,
    const int* __restrict__ barm, const int* __restrict__ posm,
    const int* __restrict__ octm, const int* __restrict__ semim,
    unsigned short* __restrict__ biasg) {
    int fid = blockIdx.x;
    int b = (fid >= 544) ? 1 : 0;
    int f = fid - b * 544;
    int ti, tj;
    if (f >= 480) { int rr = f - 480; ti = 60 + (rr >> 4); tj = rr & 15; }
    else {
        int g = (int)(0.5f * (sqrtf(1.0f + 2.0f * (float)f) - 1.0f));
        while (2 * (g + 1) * (g + 2) <= f) g++;
        while (2 * g * (g + 1) > f) g--;
        int rr = f - 2 * g * (g + 1);
        int q = rr / (g + 1);
        ti = g * 4 + q;
        tj = rr - q * (g + 1);
    }
    int i0 = ti * 16, j0 = tj * 64;

    __shared__ float2 t2[8 * 233];
    __shared__ int    pk[16 * 65];

    int t = threadIdx.x;
    int rel_lo = i0 - j0 - 63; if (rel_lo < 0) rel_lo = 0;

    for (int idx = t; idx < 231 * 8; idx += 256) {
        int s = idx >> 3, h2 = idx & 7;
        float va, vb;
        if (s < 80) {
            int src = rel_lo + s; if (src > 1023) src = 1023;
            va = Eidx[src * 16 + h2]; vb = Eidx[src * 16 + h2 + 8];
        } else if (s < 97)  { va = Ebar[(s - 80) * 16 + h2];  vb = Ebar[(s - 80) * 16 + h2 + 8]; }
        else if (s < 193)   { va = Epos[(s - 97) * 16 + h2];  vb = Epos[(s - 97) * 16 + h2 + 8]; }
        else if (s < 218)   { va = Eoct[(s - 193) * 16 + h2]; vb = Eoct[(s - 193) * 16 + h2 + 8]; }
        else                { va = Esemi[(s - 218) * 16 + h2]; vb = Esemi[(s - 218) * 16 + h2 + 8]; }
        t2[h2 * 233 + s] = make_float2(va, vb);
    }
    #pragma unroll
    for (int cc = 0; cc < 4; cc++) {
        int cell = t + cc * 256;
        int i = i0 + (cell >> 6), j = j0 + (cell & 63);
        long ij = ((long)b << 20) + ((long)i << 10) + j;
        int v = (barm[ij] + 1) | ((posm[ij] + 1) << 5) |
                ((octm[ij] + 1) << 12) | ((semim[ij] + 1) << 17);
        pk[(cell >> 6) * 65 + (cell & 63)] = v;
    }
    __syncthreads();

    int r = t & 15, h2 = (t >> 4) & 7, ah = t >> 7;
    int i = i0 + r;
    int base_rel = i - j0 - rel_lo;
    const float2* T = &t2[h2 * 233];
    long frag = (r >> 2) * 256 + (r & 3) * 4;
    unsigned short* dstL = biasg + ((((long)(b * 16 + h2)     * 64 + ti) * 16 + tj) << 10) + frag;
    unsigned short* dstH = biasg + ((((long)(b * 16 + h2 + 8) * 64 + ti) * 16 + tj) << 10) + frag;
    #pragma unroll 4
    for (int aa = 0; aa < 8; aa++) {
        int a = ah * 8 + aa;
        ushort4 ovL, ovH;
        #pragma unroll
        for (int jj = 0; jj < 4; jj++) {
            int col = a + 16 * jj;
            int p = pk[r * 65 + col];
            int sr = base_rel - col; if (sr < 0) sr = 0;
            float2 v0 = T[sr];
            float2 v1 = T[80  + (p & 31)];
            float2 v2 = T[97  + ((p >> 5)  & 127)];
            float2 v3 = T[193 + ((p >> 12) & 31)];
            float2 v4 = T[218 + ((p >> 17) & 15)];
            float xL = v0.x + v1.x + v2.x + v3.x + v4.x;
            float xH = v0.y + v1.y + v2.y + v3.y + v4.y;
            ((unsigned short*)&ovL)[jj] = f2bf(xL * 0.125f);
            ((unsigned short*)&ovH)[jj] = f2bf(xH * 0.125f);
        }
        *(ushort4*)(dstL + a * 16) = ovL;
        *(ushort4*)(dstH + a * 16) = ovH;
    }
}

// ---------------- K3/K5: bf16 GEMM, 128x128 tile, global_load_lds (m97) -------
// (unchanged from round 9 — validated)
__global__ __launch_bounds__(256) void k_gemm(
    const unsigned short* __restrict__ A,
    const unsigned short* __restrict__ B0, const unsigned short* __restrict__ B1,
    const unsigned short* __restrict__ B2,
    unsigned short* __restrict__ qd, unsigned short* __restrict__ kd,
    unsigned short* __restrict__ vtd, float* __restrict__ outf, int mode) {
    __shared__ unsigned short As[128 * 64];
    __shared__ unsigned short Bs[128 * 64];
    int md = (mode < 0) ? (int)blockIdx.z : mode;
    const unsigned short* B = (md == 1) ? B1 : (md == 2) ? B2 : B0;
    int m0 = blockIdx.x * 128, n0 = blockIdx.y * 128;
    int t = threadIdx.x;
    int w = t >> 6, lane = t & 63, g = lane >> 4, c = lane & 15;
    int wr = w >> 1, wc = w & 1;
    const int K = 1024;
    f32x4 zero = {0.f, 0.f, 0.f, 0.f};
    f32x4 acc[4][4];
    #pragma unroll
    for (int m = 0; m < 4; m++)
        #pragma unroll
        for (int n = 0; n < 4; n++) acc[m][n] = zero;

    int srow = w * 8 + (lane >> 3);
    int scol = (lane & 7) * 8;
    for (int k0 = 0; k0 < K; k0 += 64) {
        __syncthreads();
        #pragma unroll
        for (int q = 0; q < 4; q++) {
            int row = q * 32 + srow;
            __builtin_amdgcn_global_load_lds(
                (const __attribute__((address_space(1))) unsigned int*)(A + (long)(m0 + row) * K + k0 + scol),
                (__attribute__((address_space(3))) unsigned int*)&As[(q * 32 + w * 8) * 64],
                16, 0, 0);
            __builtin_amdgcn_global_load_lds(
                (const __attribute__((address_space(1))) unsigned int*)(B + (long)(n0 + row) * K + k0 + scol),
                (__attribute__((address_space(3))) unsigned int*)&Bs[(q * 32 + w * 8) * 64],
                16, 0, 0);
        }
        __syncthreads();
        #pragma unroll
        for (int kk = 0; kk < 2; kk++) {
            short8 a[4], bb[4];
            #pragma unroll
            for (int m = 0; m < 4; m++)
                a[m] = *(const short8*)&As[(wr * 64 + m * 16 + c) * 64 + kk * 32 + g * 8];
            #pragma unroll
            for (int n = 0; n < 4; n++)
                bb[n] = *(const short8*)&Bs[(wc * 64 + n * 16 + c) * 64 + kk * 32 + g * 8];
            #pragma unroll
            for (int m = 0; m < 4; m++)
                #pragma unroll
                for (int n = 0; n < 4; n++)
                    acc[m][n] = __builtin_amdgcn_mfma_f32_16x16x32_bf16(a[m], bb[n], acc[m][n], 0, 0, 0);
        }
    }

    if (md <= 1) {
        unsigned short* dst = (md == 0) ? qd : kd;
        float scale = (md == 0) ? 0.125f : 1.0f;
        #pragma unroll
        for (int m = 0; m < 4; m++) {
            #pragma unroll
            for (int r = 0; r < 4; r++) {
                int mm = m0 + wr * 64 + m * 16 + g * 4 + r;
                int bb2 = mm >> 10, ii = mm & 1023;
                #pragma unroll
                for (int n = 0; n < 4; n++) {
                    int nn = n0 + wc * 64 + n * 16 + c;
                    int hh = nn >> 6, dd = nn & 63;
                    dst[(((long)(bb2 * 16 + hh) << 10) + ii) * 64 + dd] = f2bf(acc[m][n][r] * scale);
                }
            }
        }
    } else if (md == 2) {
        #pragma unroll
        for (int m = 0; m < 4; m++) {
            int mm0 = m0 + wr * 64 + m * 16 + g * 4;
            int bb2 = mm0 >> 10, ii = mm0 & 1023;
            #pragma unroll
            for (int n = 0; n < 4; n++) {
                int nn = n0 + wc * 64 + n * 16 + c;
                int hh = nn >> 6, dd = nn & 63;
                ushort4 pkv;
                pkv.x = f2bf(acc[m][n][0]); pkv.y = f2bf(acc[m][n][1]);
                pkv.z = f2bf(acc[m][n][2]); pkv.w = f2bf(acc[m][n][3]);
                *(ushort4*)&vtd[(((long)(bb2 * 16 + hh) << 6) + dd) * 1024 + ii] = pkv;
            }
        }
    } else {
        #pragma unroll
        for (int m = 0; m < 4; m++) {
            #pragma unroll
            for (int r = 0; r < 4; r++) {
                long mm = m0 + wr * 64 + m * 16 + g * 4 + r;
                #pragma unroll
                for (int n = 0; n < 4; n++) {
                    int nn = n0 + wc * 64 + n * 16 + c;
                    outf[mm * 1024 + nn] = acc[m][n][r];
                }
            }
        }
    }
}

// ---------------- K4: flash attention, stripe-paired, pipelined ---------------
// grid 1024 = 32 stripe-pairs x 32 (b,h); block handles i-tiles (63-pid) heavy
// then (pid) light -> uniform block duration (15.75-17.25 j-tile units each).
// Inner loop: round-11 pipelined (p_lds ping-pong, K+bias reg prefetch, V
// hoisted). Fixed softmax shift m=8; parallel 4-wave combine per tile.
#define LOADT(KA, KB, BV, JT) do {                                             \
    int _j0 = (JT) * 64;                                                       \
    _Pragma("unroll")                                                          \
    for (int _s = 0; _s < 4; _s++) {                                           \
        const unsigned short* _kr = Kp + (long)(_j0 + _s * 16 + c) * 64 + g * 8; \
        KA[_s] = *(const short8*)(_kr);                                        \
        KB[_s] = *(const short8*)(_kr + 32);                                   \
    }                                                                          \
    const unsigned short* _bp = Bt + ((JT) << 10) + lane * 16;                 \
    BV[0] = *(const short8*)(_bp);                                             \
    BV[1] = *(const short8*)(_bp + 8);                                         \
} while (0)

#define BODY(KA, KB, BV, JT, POFS) do {                                        \
    int _j0 = (JT) * 64;                                                       \
    f32x4 _s[4];                                                               \
    _Pragma("unroll")                                                          \
    for (int _jj = 0; _jj < 4; _jj++) {                                        \
        _s[_jj] = __builtin_amdgcn_mfma_f32_16x16x32_bf16(q0, KA[_jj], zero, 0, 0, 0); \
        _s[_jj] = __builtin_amdgcn_mfma_f32_16x16x32_bf16(q1, KB[_jj], _s[_jj], 0, 0, 0); \
    }                                                                          \
    short8 _v0[4], _v1[4];                                                     \
    _Pragma("unroll")                                                          \
    for (int _dd = 0; _dd < 4; _dd++) {                                        \
        const unsigned short* _vb = Vp + (long)(_dd * 16 + c) * 1024 + _j0 + g * 8; \
        _v0[_dd] = *(const short8*)(_vb);                                      \
        _v1[_dd] = *(const short8*)(_vb + 32);                                 \
    }                                                                          \
    _Pragma("unroll")                                                          \
    for (int _r = 0; _r < 4; _r++) {                                           \
        _Pragma("unroll")                                                      \
        for (int _jj = 0; _jj < 4; _jj++) {                                    \
            int _idx = _r * 4 + _jj;                                           \
            float _bb = (_idx < 8) ? bf2f((unsigned short)BV[0][_idx])         \
                                   : bf2f((unsigned short)BV[1][_idx - 8]);    \
            _s[_jj][_r] += _bb;                                                \
        }                                                                      \
    }                                                                          \
    if ((JT) == nj - 1) {                                                      \
        _Pragma("unroll")                                                      \
        for (int _r = 0; _r < 4; _r++) {                                       \
            int _i = i0 + g * 4 + _r;                                          \
            _Pragma("unroll")                                                  \
            for (int _jj = 0; _jj < 4; _jj++)                                  \
                if (_j0 + _jj * 16 + c > _i) _s[_jj][_r] = -1e9f;              \
        }                                                                      \
    }                                                                          \
    unsigned short* _p = (unsigned short*)(wbase + (POFS));                    \
    _Pragma("unroll")                                                          \
    for (int _r = 0; _r < 4; _r++) {                                           \
        _Pragma("unroll")                                                      \
        for (int _jj = 0; _jj < 4; _jj++) {                                    \
            float _pv = exp2f(__builtin_fmaf(_s[_jj][_r], LOG2E, -8.0f * LOG2E)); \
            l[_r] += _pv;                                                      \
            union { float f; unsigned int u; } _pu; _pu.f = _pv;               \
            _p[(g * 4 + _r) * 72 + c + 16 * _jj] = (unsigned short)(_pu.u >> 16); \
        }                                                                      \
    }                                                                          \
    short8 _pa0 = *(const short8*)&_p[c * 72 + g * 8];                         \
    short8 _pa1 = *(const short8*)&_p[c * 72 + 32 + g * 8];                    \
    _Pragma("unroll")                                                          \
    for (int _dd = 0; _dd < 4; _dd++) {                                        \
        o[_dd] = __builtin_amdgcn_mfma_f32_16x16x32_bf16(_pa0, _v0[_dd], o[_dd], 0, 0, 0); \
        o[_dd] = __builtin_amdgcn_mfma_f32_16x16x32_bf16(_pa1, _v1[_dd], o[_dd], 0, 0, 0); \
    }                                                                          \
} while (0)

__global__ __launch_bounds__(256) void k_attn(
    const unsigned short* __restrict__ Qs, const unsigned short* __restrict__ Ks,
    const unsigned short* __restrict__ VTs, const unsigned short* __restrict__ biasg,
    unsigned short* __restrict__ Os) {
    // per-wave 5632B: loop: p_lds ping-pong 2x[16][72] u16 at +0/+2304;
    // combine: oc 64x17 f32 (overlays p_lds) + lc 64x5 f32 at +4352.
    __shared__ char smem[4 * 5632];
    int bid = blockIdx.x;
    int pid = bid >> 5;                 // 0..31 stripe pair
    int bh = bid & 31;
    int b = bh >> 4, h = bh & 15;
    int w = threadIdx.x >> 6;
    int lane = threadIdx.x & 63;
    int g = lane >> 4, c = lane & 15;

    char* wbase = smem + w * 5632;

    long plane = ((long)bh) << 16;
    const unsigned short* Qp = Qs + plane;
    const unsigned short* Kp = Ks + plane;
    const unsigned short* Vp = VTs + plane;             // [64 d][1024 j]

    f32x4 zero = {0.f, 0.f, 0.f, 0.f};

    #pragma unroll
    for (int tile = 0; tile < 2; tile++) {
        int it = tile ? pid : (63 - pid);               // heavy first
        int i0 = it * 16;
        const unsigned short* Bt = biasg + (((long)bh * 64 + it) << 14);

        short8 q0 = *(const short8*)(Qp + (long)(i0 + c) * 64 + g * 8);
        short8 q1 = *(const short8*)(Qp + (long)(i0 + c) * 64 + 32 + g * 8);

        f32x4 o[4]; o[0] = zero; o[1] = zero; o[2] = zero; o[3] = zero;
        float l[4] = {0.f, 0.f, 0.f, 0.f};

        int nj = (it >> 2) + 1;        // 64-col tiles
        short8 kaA[4], kbA[4], bvA[2];
        short8 kaB[4], kbB[4], bvB[2];
        if (w < nj) LOADT(kaA, kbA, bvA, w);
        for (int jt = w; jt < nj; jt += 8) {
            if (jt + 4 < nj) LOADT(kaB, kbB, bvB, jt + 4);
            BODY(kaA, kbA, bvA, jt, 0);
            if (jt + 4 < nj) {
                if (jt + 8 < nj) LOADT(kaA, kbA, bvA, jt + 8);
                BODY(kaB, kbB, bvB, jt + 4, 2304);
            }
        }
        // ---- cross-wave combine: plain sums; all 4 waves participate ----
        float* oc = (float*)wbase;                 // [64][17]
        float* lc = (float*)(wbase + 4352);        // [64][5]
        #pragma unroll
        for (int dd = 0; dd < 4; dd++)
            #pragma unroll
            for (int r = 0; r < 4; r++)
                oc[lane * 17 + dd * 4 + r] = o[dd][r];
        #pragma unroll
        for (int r = 0; r < 4; r++) lc[lane * 5 + r] = l[r];
        __syncthreads();

        {
            int r = w;                              // wave w handles residue r=w
            float lv = 0.f;
            #pragma unroll
            for (int ww = 0; ww < 4; ww++)
                lv += ((const float*)(smem + ww * 5632 + 4352))[lane * 5 + r];
            lv += __shfl_xor(lv, 1); lv += __shfl_xor(lv, 2);
            lv += __shfl_xor(lv, 4); lv += __shfl_xor(lv, 8);
            float linv = 1.0f / lv;
            int i = i0 + g * 4 + r;
            unsigned short* op = Os + ((long)(b * 1024 + i)) * 1024 + h * 64;
            #pragma unroll
            for (int dd = 0; dd < 4; dd++) {
                float ov = 0.f;
                #pragma unroll
                for (int ww = 0; ww < 4; ww++)
                    ov += ((const float*)(smem + ww * 5632))[lane * 17 + dd * 4 + r];
                op[dd * 16 + c] = f2bf(ov * linv);
            }
        }
        __syncthreads();   // protect oc/p_lds overlay before next tile
    }
}

// ------------------------------- launch ---------------------------------------
extern "C" void kernel_launch(void* const* d_in, const int* in_sizes, int n_in,
                              void* d_out, int out_size, void* d_ws, size_t ws_size,
                              hipStream_t stream) {
    const float* x     = (const float*)d_in[0];
    const float* Wq    = (const float*)d_in[1];
    const float* Wk    = (const float*)d_in[2];
    const float* Wv    = (const float*)d_in[3];
    const float* Wo    = (const float*)d_in[4];
    const float* Eidx  = (const float*)d_in[5];
    const float* Ebar  = (const float*)d_in[6];
    const float* Epos  = (const float*)d_in[7];
    const float* Eoct  = (const float*)d_in[8];
    const float* Esemi = (const float*)d_in[9];
    const int* barm    = (const int*)d_in[10];
    const int* posm    = (const int*)d_in[11];
    const int* octm    = (const int*)d_in[12];
    const int* semim   = (const int*)d_in[13];
    float* outf = (float*)d_out;

    unsigned short* w = (unsigned short*)d_ws;
    unsigned short* XB   = w;                   // 2M el
    unsigned short* WQB  = w + 2097152;         // 1M el each
    unsigned short* WKB  = w + 3145728;
    unsigned short* WVB  = w + 4194304;
    unsigned short* WOB  = w + 5242880;
    unsigned short* QS   = w + 6291456;         // (b,h,n,d)
    unsigned short* KS   = w + 8388608;
    unsigned short* VTS  = w + 10485760;        // (b,h,d,n)
    unsigned short* OS   = w + 12582912;        // (b,n,h*d)
    unsigned short* BIAS = w + 14680064;        // 32M el, fragment tiles

    k_convert<<<6144, 256, 0, stream>>>(x, Wq, Wk, Wv, Wo, w);
    k_bias<<<1088, 256, 0, stream>>>(Eidx, Ebar, Epos, Eoct, Esemi,
                                     barm, posm, octm, semim, BIAS);
    k_gemm<<<dim3(16, 8, 3), 256, 0, stream>>>(XB, WQB, WKB, WVB,
                                               QS, KS, VTS, nullptr, -1);
    k_attn<<<1024, 256, 0, stream>>>(QS, KS, VTS, BIAS, OS);
    k_gemm<<<dim3(16, 8, 1), 256, 0, stream>>>(OS, WOB, WOB, WOB,
                                               QS, KS, VTS, outf, 3);
}

// Round 13
// 110.129 us; speedup vs baseline: 1.1445x; 1.1445x over previous
//
#include <hip/hip_runtime.h>
#include <cstdint>
#include <math.h>

typedef __attribute__((ext_vector_type(8))) short short8;
typedef __attribute__((ext_vector_type(4))) float f32x4;

#define LOG2E 1.44269504088896340736f

static __device__ __forceinline__ float bf2f(unsigned short u) {
    union { unsigned int i; float f; } v; v.i = ((unsigned int)u) << 16; return v.f;
}
static __device__ __forceinline__ unsigned short f2bf(float f) {
    union { float f; unsigned int i; } v; v.f = f;
    unsigned int r = v.i + 0x7FFF + ((v.i >> 16) & 1);
    return (unsigned short)(r >> 16);
}

// ---------------- K1: fp32 -> bf16 convert (x, Wq, Wk, Wv, Wo) ----------------
__global__ __launch_bounds__(256) void k_convert(
    const float* __restrict__ x, const float* __restrict__ wq,
    const float* __restrict__ wk, const float* __restrict__ wv,
    const float* __restrict__ wo, unsigned short* __restrict__ dst) {
    long t = (long)blockIdx.x * 256 + threadIdx.x;
    long base = t * 4;
    const long NX = 2097152, NW = 1048576;
    const float* src; long off;
    if (base < NX)            { src = x;  off = base; }
    else if (base < NX + NW)  { src = wq; off = base - NX; }
    else if (base < NX + 2*NW){ src = wk; off = base - NX - NW; }
    else if (base < NX + 3*NW){ src = wv; off = base - NX - 2*NW; }
    else                      { src = wo; off = base - NX - 3*NW; }
    float4 v = *(const float4*)(src + off);
    ushort4 o;
    o.x = f2bf(v.x); o.y = f2bf(v.y); o.z = f2bf(v.z); o.w = f2bf(v.w);
    *(ushort4*)(dst + base) = o;
}

// ---------------- K2: bias materialization, compact grid + dual-h float2 ------
// (unchanged from round 9 — validated)
__global__ __launch_bounds__(256) void k_bias(
    const float* __restrict__ Eidx, const float* __restrict__ Ebar,
    const float* __restrict__ Epos, const float* __restrict__ Eoct,
    const float* __restrict__ Esemi,
    const int* __restrict__ barm, const int* __restrict__ posm,
    const int* __restrict__ octm, const int* __restrict__ semim,
    unsigned short* __restrict__ biasg) {
    int fid = blockIdx.x;
    int b = (fid >= 544) ? 1 : 0;
    int f = fid - b * 544;
    int ti, tj;
    if (f >= 480) { int rr = f - 480; ti = 60 + (rr >> 4); tj = rr & 15; }
    else {
        int g = (int)(0.5f * (sqrtf(1.0f + 2.0f * (float)f) - 1.0f));
        while (2 * (g + 1) * (g + 2) <= f) g++;
        while (2 * g * (g + 1) > f) g--;
        int rr = f - 2 * g * (g + 1);
        int q = rr / (g + 1);
        ti = g * 4 + q;
        tj = rr - q * (g + 1);
    }
    int i0 = ti * 16, j0 = tj * 64;

    __shared__ float2 t2[8 * 233];
    __shared__ int    pk[16 * 65];

    int t = threadIdx.x;
    int rel_lo = i0 - j0 - 63; if (rel_lo < 0) rel_lo = 0;

    for (int idx = t; idx < 231 * 8; idx += 256) {
        int s = idx >> 3, h2 = idx & 7;
        float va, vb;
        if (s < 80) {
            int src = rel_lo + s; if (src > 1023) src = 1023;
            va = Eidx[src * 16 + h2]; vb = Eidx[src * 16 + h2 + 8];
        } else if (s < 97)  { va = Ebar[(s - 80) * 16 + h2];  vb = Ebar[(s - 80) * 16 + h2 + 8]; }
        else if (s < 193)   { va = Epos[(s - 97) * 16 + h2];  vb = Epos[(s - 97) * 16 + h2 + 8]; }
        else if (s < 218)   { va = Eoct[(s - 193) * 16 + h2]; vb = Eoct[(s - 193) * 16 + h2 + 8]; }
        else                { va = Esemi[(s - 218) * 16 + h2]; vb = Esemi[(s - 218) * 16 + h2 + 8]; }
        t2[h2 * 233 + s] = make_float2(va, vb);
    }
    #pragma unroll
    for (int cc = 0; cc < 4; cc++) {
        int cell = t + cc * 256;
        int i = i0 + (cell >> 6), j = j0 + (cell & 63);
        long ij = ((long)b << 20) + ((long)i << 10) + j;
        int v = (barm[ij] + 1) | ((posm[ij] + 1) << 5) |
                ((octm[ij] + 1) << 12) | ((semim[ij] + 1) << 17);
        pk[(cell >> 6) * 65 + (cell & 63)] = v;
    }
    __syncthreads();

    int r = t & 15, h2 = (t >> 4) & 7, ah = t >> 7;
    int i = i0 + r;
    int base_rel = i - j0 - rel_lo;
    const float2* T = &t2[h2 * 233];
    long frag = (r >> 2) * 256 + (r & 3) * 4;
    unsigned short* dstL = biasg + ((((long)(b * 16 + h2)     * 64 + ti) * 16 + tj) << 10) + frag;
    unsigned short* dstH = biasg + ((((long)(b * 16 + h2 + 8) * 64 + ti) * 16 + tj) << 10) + frag;
    #pragma unroll 4
    for (int aa = 0; aa < 8; aa++) {
        int a = ah * 8 + aa;
        ushort4 ovL, ovH;
        #pragma unroll
        for (int jj = 0; jj < 4; jj++) {
            int col = a + 16 * jj;
            int p = pk[r * 65 + col];
            int sr = base_rel - col; if (sr < 0) sr = 0;
            float2 v0 = T[sr];
            float2 v1 = T[80  + (p & 31)];
            float2 v2 = T[97  + ((p >> 5)  & 127)];
            float2 v3 = T[193 + ((p >> 12) & 31)];
            float2 v4 = T[218 + ((p >> 17) & 15)];
            float xL = v0.x + v1.x + v2.x + v3.x + v4.x;
            float xH = v0.y + v1.y + v2.y + v3.y + v4.y;
            ((unsigned short*)&ovL)[jj] = f2bf(xL * 0.125f);
            ((unsigned short*)&ovH)[jj] = f2bf(xH * 0.125f);
        }
        *(ushort4*)(dstL + a * 16) = ovL;
        *(ushort4*)(dstH + a * 16) = ovH;
    }
}

// ---------------- K3/K5: bf16 GEMM, 128x64 tile, global_load_lds --------------
// C[M][N] = A[M][1024] * B[N][1024]^T. Tile 128(M)x64(N): QKV grid (16,16,3) =
// 768 blocks = 3/CU balanced (was 384 = 1.5/CU). 4 waves, wave = 64x32 sub-tile.
__global__ __launch_bounds__(256) void k_gemm(
    const unsigned short* __restrict__ A,
    const unsigned short* __restrict__ B0, const unsigned short* __restrict__ B1,
    const unsigned short* __restrict__ B2,
    unsigned short* __restrict__ qd, unsigned short* __restrict__ kd,
    unsigned short* __restrict__ vtd, float* __restrict__ outf, int mode) {
    __shared__ unsigned short As[128 * 64];   // 16 KB, linear (gload_lds dest)
    __shared__ unsigned short Bs[64 * 64];    // 8 KB
    int md = (mode < 0) ? (int)blockIdx.z : mode;
    const unsigned short* B = (md == 1) ? B1 : (md == 2) ? B2 : B0;
    int m0 = blockIdx.x * 128, n0 = blockIdx.y * 64;
    int t = threadIdx.x;
    int w = t >> 6, lane = t & 63, g = lane >> 4, c = lane & 15;
    int wr = w >> 1, wc = w & 1;              // wave: rows wr*64+, cols wc*32+
    const int K = 1024;
    f32x4 zero = {0.f, 0.f, 0.f, 0.f};
    f32x4 acc[4][2];
    #pragma unroll
    for (int m = 0; m < 4; m++)
        #pragma unroll
        for (int n = 0; n < 2; n++) acc[m][n] = zero;

    int srow = w * 8 + (lane >> 3);      // + q*32
    int scol = (lane & 7) * 8;           // element offset within BK
    for (int k0 = 0; k0 < K; k0 += 64) {
        __syncthreads();
        #pragma unroll
        for (int q = 0; q < 4; q++) {
            int row = q * 32 + srow;
            __builtin_amdgcn_global_load_lds(
                (const __attribute__((address_space(1))) unsigned int*)(A + (long)(m0 + row) * K + k0 + scol),
                (__attribute__((address_space(3))) unsigned int*)&As[(q * 32 + w * 8) * 64],
                16, 0, 0);
        }
        #pragma unroll
        for (int q = 0; q < 2; q++) {
            int row = q * 32 + srow;
            __builtin_amdgcn_global_load_lds(
                (const __attribute__((address_space(1))) unsigned int*)(B + (long)(n0 + row) * K + k0 + scol),
                (__attribute__((address_space(3))) unsigned int*)&Bs[(q * 32 + w * 8) * 64],
                16, 0, 0);
        }
        __syncthreads();
        #pragma unroll
        for (int kk = 0; kk < 2; kk++) {
            short8 a[4], bb[2];
            #pragma unroll
            for (int m = 0; m < 4; m++)
                a[m] = *(const short8*)&As[(wr * 64 + m * 16 + c) * 64 + kk * 32 + g * 8];
            #pragma unroll
            for (int n = 0; n < 2; n++)
                bb[n] = *(const short8*)&Bs[(wc * 32 + n * 16 + c) * 64 + kk * 32 + g * 8];
            #pragma unroll
            for (int m = 0; m < 4; m++)
                #pragma unroll
                for (int n = 0; n < 2; n++)
                    acc[m][n] = __builtin_amdgcn_mfma_f32_16x16x32_bf16(a[m], bb[n], acc[m][n], 0, 0, 0);
        }
    }

    if (md <= 1) {
        unsigned short* dst = (md == 0) ? qd : kd;
        float scale = (md == 0) ? 0.125f : 1.0f;
        #pragma unroll
        for (int m = 0; m < 4; m++) {
            #pragma unroll
            for (int r = 0; r < 4; r++) {
                int mm = m0 + wr * 64 + m * 16 + g * 4 + r;
                int bb2 = mm >> 10, ii = mm & 1023;
                #pragma unroll
                for (int n = 0; n < 2; n++) {
                    int nn = n0 + wc * 32 + n * 16 + c;
                    int hh = nn >> 6, dd = nn & 63;
                    dst[(((long)(bb2 * 16 + hh) << 10) + ii) * 64 + dd] = f2bf(acc[m][n][r] * scale);
                }
            }
        }
    } else if (md == 2) {
        #pragma unroll
        for (int m = 0; m < 4; m++) {
            int mm0 = m0 + wr * 64 + m * 16 + g * 4;
            int bb2 = mm0 >> 10, ii = mm0 & 1023;
            #pragma unroll
            for (int n = 0; n < 2; n++) {
                int nn = n0 + wc * 32 + n * 16 + c;
                int hh = nn >> 6, dd = nn & 63;
                ushort4 pkv;
                pkv.x = f2bf(acc[m][n][0]); pkv.y = f2bf(acc[m][n][1]);
                pkv.z = f2bf(acc[m][n][2]); pkv.w = f2bf(acc[m][n][3]);
                *(ushort4*)&vtd[(((long)(bb2 * 16 + hh) << 6) + dd) * 1024 + ii] = pkv;
            }
        }
    } else {
        #pragma unroll
        for (int m = 0; m < 4; m++) {
            #pragma unroll
            for (int r = 0; r < 4; r++) {
                long mm = m0 + wr * 64 + m * 16 + g * 4 + r;
                #pragma unroll
                for (int n = 0; n < 2; n++) {
                    int nn = n0 + wc * 32 + n * 16 + c;
                    outf[mm * 1024 + nn] = acc[m][n][r];
                }
            }
        }
    }
}

// ---------------- K4: flash attention, KVBLK=64, pipelined (dbuf + prefetch) --
// (byte-exact revert to round 11 — proven best ~39 us, VGPR 88)
#define LOADT(KA, KB, BV, JT) do {                                             \
    int _j0 = (JT) * 64;                                                       \
    _Pragma("unroll")                                                          \
    for (int _s = 0; _s < 4; _s++) {                                           \
        const unsigned short* _kr = Kp + (long)(_j0 + _s * 16 + c) * 64 + g * 8; \
        KA[_s] = *(const short8*)(_kr);                                        \
        KB[_s] = *(const short8*)(_kr + 32);                                   \
    }                                                                          \
    const unsigned short* _bp = Bt + ((JT) << 10) + lane * 16;                 \
    BV[0] = *(const short8*)(_bp);                                             \
    BV[1] = *(const short8*)(_bp + 8);                                         \
} while (0)

#define BODY(KA, KB, BV, JT, POFS) do {                                        \
    int _j0 = (JT) * 64;                                                       \
    f32x4 _s[4];                                                               \
    _Pragma("unroll")                                                          \
    for (int _jj = 0; _jj < 4; _jj++) {                                        \
        _s[_jj] = __builtin_amdgcn_mfma_f32_16x16x32_bf16(q0, KA[_jj], zero, 0, 0, 0); \
        _s[_jj] = __builtin_amdgcn_mfma_f32_16x16x32_bf16(q1, KB[_jj], _s[_jj], 0, 0, 0); \
    }                                                                          \
    short8 _v0[4], _v1[4];                                                     \
    _Pragma("unroll")                                                          \
    for (int _dd = 0; _dd < 4; _dd++) {                                        \
        const unsigned short* _vb = Vp + (long)(_dd * 16 + c) * 1024 + _j0 + g * 8; \
        _v0[_dd] = *(const short8*)(_vb);                                      \
        _v1[_dd] = *(const short8*)(_vb + 32);                                 \
    }                                                                          \
    _Pragma("unroll")                                                          \
    for (int _r = 0; _r < 4; _r++) {                                           \
        _Pragma("unroll")                                                      \
        for (int _jj = 0; _jj < 4; _jj++) {                                    \
            int _idx = _r * 4 + _jj;                                           \
            float _bb = (_idx < 8) ? bf2f((unsigned short)BV[0][_idx])         \
                                   : bf2f((unsigned short)BV[1][_idx - 8]);    \
            _s[_jj][_r] += _bb;                                                \
        }                                                                      \
    }                                                                          \
    if ((JT) == nj - 1) {                                                      \
        _Pragma("unroll")                                                      \
        for (int _r = 0; _r < 4; _r++) {                                       \
            int _i = i0 + g * 4 + _r;                                          \
            _Pragma("unroll")                                                  \
            for (int _jj = 0; _jj < 4; _jj++)                                  \
                if (_j0 + _jj * 16 + c > _i) _s[_jj][_r] = -1e9f;              \
        }                                                                      \
    }                                                                          \
    unsigned short* _p = (unsigned short*)(wbase + (POFS));                    \
    _Pragma("unroll")                                                          \
    for (int _r = 0; _r < 4; _r++) {                                           \
        _Pragma("unroll")                                                      \
        for (int _jj = 0; _jj < 4; _jj++) {                                    \
            float _pv = exp2f(__builtin_fmaf(_s[_jj][_r], LOG2E, -8.0f * LOG2E)); \
            l[_r] += _pv;                                                      \
            union { float f; unsigned int u; } _pu; _pu.f = _pv;               \
            _p[(g * 4 + _r) * 72 + c + 16 * _jj] = (unsigned short)(_pu.u >> 16); \
        }                                                                      \
    }                                                                          \
    short8 _pa0 = *(const short8*)&_p[c * 72 + g * 8];                         \
    short8 _pa1 = *(const short8*)&_p[c * 72 + 32 + g * 8];                    \
    _Pragma("unroll")                                                          \
    for (int _dd = 0; _dd < 4; _dd++) {                                        \
        o[_dd] = __builtin_amdgcn_mfma_f32_16x16x32_bf16(_pa0, _v0[_dd], o[_dd], 0, 0, 0); \
        o[_dd] = __builtin_amdgcn_mfma_f32_16x16x32_bf16(_pa1, _v1[_dd], o[_dd], 0, 0, 0); \
    }                                                                          \
} while (0)

__global__ __launch_bounds__(256) void k_attn(
    const unsigned short* __restrict__ Qs, const unsigned short* __restrict__ Ks,
    const unsigned short* __restrict__ VTs, const unsigned short* __restrict__ biasg,
    unsigned short* __restrict__ Os) {
    __shared__ char smem[4 * 5632];
    int bid = blockIdx.x;
    int it = 63 - (bid >> 5);          // heavy stripes dispatched first
    int bh = bid & 31;
    int b = bh >> 4, h = bh & 15;
    int w = threadIdx.x >> 6;
    int lane = threadIdx.x & 63;
    int g = lane >> 4, c = lane & 15;
    int i0 = it * 16;

    char* wbase = smem + w * 5632;

    long plane = ((long)bh) << 16;
    const unsigned short* Qp = Qs + plane;
    const unsigned short* Kp = Ks + plane;
    const unsigned short* Vp = VTs + plane;             // [64 d][1024 j]
    const unsigned short* Bt = biasg + (((long)bh * 64 + it) << 14);

    short8 q0 = *(const short8*)(Qp + (long)(i0 + c) * 64 + g * 8);
    short8 q1 = *(const short8*)(Qp + (long)(i0 + c) * 64 + 32 + g * 8);

    f32x4 zero = {0.f, 0.f, 0.f, 0.f};
    f32x4 o[4]; o[0] = zero; o[1] = zero; o[2] = zero; o[3] = zero;
    float l[4] = {0.f, 0.f, 0.f, 0.f};

    int nj = (it >> 2) + 1;            // 64-col tiles
    short8 kaA[4], kbA[4], bvA[2];
    short8 kaB[4], kbB[4], bvB[2];
    if (w < nj) LOADT(kaA, kbA, bvA, w);
    for (int jt = w; jt < nj; jt += 8) {
        if (jt + 4 < nj) LOADT(kaB, kbB, bvB, jt + 4);
        BODY(kaA, kbA, bvA, jt, 0);
        if (jt + 4 < nj) {
            if (jt + 8 < nj) LOADT(kaA, kbA, bvA, jt + 8);
            BODY(kaB, kbB, bvB, jt + 4, 2304);
        }
    }
    // ---- cross-wave combine: plain sums; all 4 waves participate ----
    float* oc = (float*)wbase;                 // [64][17]
    float* lc = (float*)(wbase + 4352);        // [64][5]
    #pragma unroll
    for (int dd = 0; dd < 4; dd++)
        #pragma unroll
        for (int r = 0; r < 4; r++)
            oc[lane * 17 + dd * 4 + r] = o[dd][r];
    #pragma unroll
    for (int r = 0; r < 4; r++) lc[lane * 5 + r] = l[r];
    __syncthreads();

    {
        int r = w;                              // wave w handles residue r=w
        float lv = 0.f;
        #pragma unroll
        for (int ww = 0; ww < 4; ww++)
            lv += ((const float*)(smem + ww * 5632 + 4352))[lane * 5 + r];
        lv += __shfl_xor(lv, 1); lv += __shfl_xor(lv, 2);
        lv += __shfl_xor(lv, 4); lv += __shfl_xor(lv, 8);
        float linv = 1.0f / lv;
        int i = i0 + g * 4 + r;
        unsigned short* op = Os + ((long)(b * 1024 + i)) * 1024 + h * 64;
        #pragma unroll
        for (int dd = 0; dd < 4; dd++) {
            float ov = 0.f;
            #pragma unroll
            for (int ww = 0; ww < 4; ww++)
                ov += ((const float*)(smem + ww * 5632))[lane * 17 + dd * 4 + r];
            op[dd * 16 + c] = f2bf(ov * linv);
        }
    }
}

// ------------------------------- launch ---------------------------------------
extern "C" void kernel_launch(void* const* d_in, const int* in_sizes, int n_in,
                              void* d_out, int out_size, void* d_ws, size_t ws_size,
                              hipStream_t stream) {
    const float* x     = (const float*)d_in[0];
    const float* Wq    = (const float*)d_in[1];
    const float* Wk    = (const float*)d_in[2];
    const float* Wv    = (const float*)d_in[3];
    const float* Wo    = (const float*)d_in[4];
    const float* Eidx  = (const float*)d_in[5];
    const float* Ebar  = (const float*)d_in[6];
    const float* Epos  = (const float*)d_in[7];
    const float* Eoct  = (const float*)d_in[8];
    const float* Esemi = (const float*)d_in[9];
    const int* barm    = (const int*)d_in[10];
    const int* posm    = (const int*)d_in[11];
    const int* octm    = (const int*)d_in[12];
    const int* semim   = (const int*)d_in[13];
    float* outf = (float*)d_out;

    unsigned short* w = (unsigned short*)d_ws;
    unsigned short* XB   = w;                   // 2M el
    unsigned short* WQB  = w + 2097152;         // 1M el each
    unsigned short* WKB  = w + 3145728;
    unsigned short* WVB  = w + 4194304;
    unsigned short* WOB  = w + 5242880;
    unsigned short* QS   = w + 6291456;         // (b,h,n,d)
    unsigned short* KS   = w + 8388608;
    unsigned short* VTS  = w + 10485760;        // (b,h,d,n)
    unsigned short* OS   = w + 12582912;        // (b,n,h*d)
    unsigned short* BIAS = w + 14680064;        // 32M el, fragment tiles

    k_convert<<<6144, 256, 0, stream>>>(x, Wq, Wk, Wv, Wo, w);
    k_bias<<<1088, 256, 0, stream>>>(Eidx, Ebar, Epos, Eoct, Esemi,
                                     barm, posm, octm, semim, BIAS);
    k_gemm<<<dim3(16, 16, 3), 256, 0, stream>>>(XB, WQB, WKB, WVB,
                                                QS, KS, VTS, nullptr, -1);
    k_attn<<<2048, 256, 0, stream>>>(QS, KS, VTS, BIAS, OS);
    k_gemm<<<dim3(16, 16, 1), 256, 0, stream>>>(OS, WOB, WOB, WOB,
                                                QS, KS, VTS, outf, 3);
}

// Round 14
// 105.275 us; speedup vs baseline: 1.1972x; 1.0461x over previous
//
#include <hip/hip_runtime.h>
#include <cstdint>
#include <math.h>

typedef __attribute__((ext_vector_type(8))) short short8;
typedef __attribute__((ext_vector_type(4))) float f32x4;

#define LOG2E 1.44269504088896340736f

static __device__ __forceinline__ float bf2f(unsigned short u) {
    union { unsigned int i; float f; } v; v.i = ((unsigned int)u) << 16; return v.f;
}
static __device__ __forceinline__ unsigned short f2bf(float f) {
    union { float f; unsigned int i; } v; v.f = f;
    unsigned int r = v.i + 0x7FFF + ((v.i >> 16) & 1);
    return (unsigned short)(r >> 16);
}

// ---------------- K1: fused prep = bias(1088 blocks first) + convert(6144) ----
// bias body: compact-grid dual-h float2 gathers (validated round 9).
// convert body: fp32->bf16 stream (validated round 3). Independent kernels
// fused into one dispatch so convert hides under bias (single-stream overlap).
__global__ __launch_bounds__(256) void k_prep(
    const float* __restrict__ x, const float* __restrict__ wq,
    const float* __restrict__ wk, const float* __restrict__ wv,
    const float* __restrict__ wo, unsigned short* __restrict__ dstconv,
    const float* __restrict__ Eidx, const float* __restrict__ Ebar,
    const float* __restrict__ Epos, const float* __restrict__ Eoct,
    const float* __restrict__ Esemi,
    const int* __restrict__ barm, const int* __restrict__ posm,
    const int* __restrict__ octm, const int* __restrict__ semim,
    unsigned short* __restrict__ biasg) {
    __shared__ float2 t2[8 * 233];
    __shared__ int    pk[16 * 65];

    if (blockIdx.x >= 1088) {
        // ---------------- convert body ----------------
        long t = (long)(blockIdx.x - 1088) * 256 + threadIdx.x;
        long base = t * 4;
        const long NX = 2097152, NW = 1048576;
        const float* src; long off;
        if (base < NX)            { src = x;  off = base; }
        else if (base < NX + NW)  { src = wq; off = base - NX; }
        else if (base < NX + 2*NW){ src = wk; off = base - NX - NW; }
        else if (base < NX + 3*NW){ src = wv; off = base - NX - 2*NW; }
        else                      { src = wo; off = base - NX - 3*NW; }
        float4 v = *(const float4*)(src + off);
        ushort4 o;
        o.x = f2bf(v.x); o.y = f2bf(v.y); o.z = f2bf(v.z); o.w = f2bf(v.w);
        *(ushort4*)(dstconv + base) = o;
        return;
    }
    // ---------------- bias body ----------------
    int fid = blockIdx.x;
    int b = (fid >= 544) ? 1 : 0;
    int f = fid - b * 544;
    int ti, tj;
    if (f >= 480) { int rr = f - 480; ti = 60 + (rr >> 4); tj = rr & 15; }
    else {
        int g = (int)(0.5f * (sqrtf(1.0f + 2.0f * (float)f) - 1.0f));
        while (2 * (g + 1) * (g + 2) <= f) g++;
        while (2 * g * (g + 1) > f) g--;
        int rr = f - 2 * g * (g + 1);
        int q = rr / (g + 1);
        ti = g * 4 + q;
        tj = rr - q * (g + 1);
    }
    int i0 = ti * 16, j0 = tj * 64;

    int t = threadIdx.x;
    int rel_lo = i0 - j0 - 63; if (rel_lo < 0) rel_lo = 0;

    for (int idx = t; idx < 231 * 8; idx += 256) {
        int s = idx >> 3, h2 = idx & 7;
        float va, vb;
        if (s < 80) {
            int src = rel_lo + s; if (src > 1023) src = 1023;
            va = Eidx[src * 16 + h2]; vb = Eidx[src * 16 + h2 + 8];
        } else if (s < 97)  { va = Ebar[(s - 80) * 16 + h2];  vb = Ebar[(s - 80) * 16 + h2 + 8]; }
        else if (s < 193)   { va = Epos[(s - 97) * 16 + h2];  vb = Epos[(s - 97) * 16 + h2 + 8]; }
        else if (s < 218)   { va = Eoct[(s - 193) * 16 + h2]; vb = Eoct[(s - 193) * 16 + h2 + 8]; }
        else                { va = Esemi[(s - 218) * 16 + h2]; vb = Esemi[(s - 218) * 16 + h2 + 8]; }
        t2[h2 * 233 + s] = make_float2(va, vb);
    }
    #pragma unroll
    for (int cc = 0; cc < 4; cc++) {
        int cell = t + cc * 256;
        int i = i0 + (cell >> 6), j = j0 + (cell & 63);
        long ij = ((long)b << 20) + ((long)i << 10) + j;
        int v = (barm[ij] + 1) | ((posm[ij] + 1) << 5) |
                ((octm[ij] + 1) << 12) | ((semim[ij] + 1) << 17);
        pk[(cell >> 6) * 65 + (cell & 63)] = v;
    }
    __syncthreads();

    int r = t & 15, h2 = (t >> 4) & 7, ah = t >> 7;
    int i = i0 + r;
    int base_rel = i - j0 - rel_lo;
    const float2* T = &t2[h2 * 233];
    long frag = (r >> 2) * 256 + (r & 3) * 4;
    unsigned short* dstL = biasg + ((((long)(b * 16 + h2)     * 64 + ti) * 16 + tj) << 10) + frag;
    unsigned short* dstH = biasg + ((((long)(b * 16 + h2 + 8) * 64 + ti) * 16 + tj) << 10) + frag;
    #pragma unroll 4
    for (int aa = 0; aa < 8; aa++) {
        int a = ah * 8 + aa;
        ushort4 ovL, ovH;
        #pragma unroll
        for (int jj = 0; jj < 4; jj++) {
            int col = a + 16 * jj;
            int p = pk[r * 65 + col];
            int sr = base_rel - col; if (sr < 0) sr = 0;
            float2 v0 = T[sr];
            float2 v1 = T[80  + (p & 31)];
            float2 v2 = T[97  + ((p >> 5)  & 127)];
            float2 v3 = T[193 + ((p >> 12) & 31)];
            float2 v4 = T[218 + ((p >> 17) & 15)];
            float xL = v0.x + v1.x + v2.x + v3.x + v4.x;
            float xH = v0.y + v1.y + v2.y + v3.y + v4.y;
            ((unsigned short*)&ovL)[jj] = f2bf(xL * 0.125f);
            ((unsigned short*)&ovH)[jj] = f2bf(xH * 0.125f);
        }
        *(ushort4*)(dstL + a * 16) = ovL;
        *(ushort4*)(dstH + a * 16) = ovH;
    }
}

// ---------------- K3/K5: bf16 GEMM, 128x64 tile, global_load_lds --------------
// (unchanged from round 13 — validated: 768/256 blocks, 3/CU / 1/CU balanced)
__global__ __launch_bounds__(256) void k_gemm(
    const unsigned short* __restrict__ A,
    const unsigned short* __restrict__ B0, const unsigned short* __restrict__ B1,
    const unsigned short* __restrict__ B2,
    unsigned short* __restrict__ qd, unsigned short* __restrict__ kd,
    unsigned short* __restrict__ vtd, float* __restrict__ outf, int mode) {
    __shared__ unsigned short As[128 * 64];
    __shared__ unsigned short Bs[64 * 64];
    int md = (mode < 0) ? (int)blockIdx.z : mode;
    const unsigned short* B = (md == 1) ? B1 : (md == 2) ? B2 : B0;
    int m0 = blockIdx.x * 128, n0 = blockIdx.y * 64;
    int t = threadIdx.x;
    int w = t >> 6, lane = t & 63, g = lane >> 4, c = lane & 15;
    int wr = w >> 1, wc = w & 1;
    const int K = 1024;
    f32x4 zero = {0.f, 0.f, 0.f, 0.f};
    f32x4 acc[4][2];
    #pragma unroll
    for (int m = 0; m < 4; m++)
        #pragma unroll
        for (int n = 0; n < 2; n++) acc[m][n] = zero;

    int srow = w * 8 + (lane >> 3);
    int scol = (lane & 7) * 8;
    for (int k0 = 0; k0 < K; k0 += 64) {
        __syncthreads();
        #pragma unroll
        for (int q = 0; q < 4; q++) {
            int row = q * 32 + srow;
            __builtin_amdgcn_global_load_lds(
                (const __attribute__((address_space(1))) unsigned int*)(A + (long)(m0 + row) * K + k0 + scol),
                (__attribute__((address_space(3))) unsigned int*)&As[(q * 32 + w * 8) * 64],
                16, 0, 0);
        }
        #pragma unroll
        for (int q = 0; q < 2; q++) {
            int row = q * 32 + srow;
            __builtin_amdgcn_global_load_lds(
                (const __attribute__((address_space(1))) unsigned int*)(B + (long)(n0 + row) * K + k0 + scol),
                (__attribute__((address_space(3))) unsigned int*)&Bs[(q * 32 + w * 8) * 64],
                16, 0, 0);
        }
        __syncthreads();
        #pragma unroll
        for (int kk = 0; kk < 2; kk++) {
            short8 a[4], bb[2];
            #pragma unroll
            for (int m = 0; m < 4; m++)
                a[m] = *(const short8*)&As[(wr * 64 + m * 16 + c) * 64 + kk * 32 + g * 8];
            #pragma unroll
            for (int n = 0; n < 2; n++)
                bb[n] = *(const short8*)&Bs[(wc * 32 + n * 16 + c) * 64 + kk * 32 + g * 8];
            #pragma unroll
            for (int m = 0; m < 4; m++)
                #pragma unroll
                for (int n = 0; n < 2; n++)
                    acc[m][n] = __builtin_amdgcn_mfma_f32_16x16x32_bf16(a[m], bb[n], acc[m][n], 0, 0, 0);
        }
    }

    if (md <= 1) {
        unsigned short* dst = (md == 0) ? qd : kd;
        float scale = (md == 0) ? 0.125f : 1.0f;
        #pragma unroll
        for (int m = 0; m < 4; m++) {
            #pragma unroll
            for (int r = 0; r < 4; r++) {
                int mm = m0 + wr * 64 + m * 16 + g * 4 + r;
                int bb2 = mm >> 10, ii = mm & 1023;
                #pragma unroll
                for (int n = 0; n < 2; n++) {
                    int nn = n0 + wc * 32 + n * 16 + c;
                    int hh = nn >> 6, dd = nn & 63;
                    dst[(((long)(bb2 * 16 + hh) << 10) + ii) * 64 + dd] = f2bf(acc[m][n][r] * scale);
                }
            }
        }
    } else if (md == 2) {
        #pragma unroll
        for (int m = 0; m < 4; m++) {
            int mm0 = m0 + wr * 64 + m * 16 + g * 4;
            int bb2 = mm0 >> 10, ii = mm0 & 1023;
            #pragma unroll
            for (int n = 0; n < 2; n++) {
                int nn = n0 + wc * 32 + n * 16 + c;
                int hh = nn >> 6, dd = nn & 63;
                ushort4 pkv;
                pkv.x = f2bf(acc[m][n][0]); pkv.y = f2bf(acc[m][n][1]);
                pkv.z = f2bf(acc[m][n][2]); pkv.w = f2bf(acc[m][n][3]);
                *(ushort4*)&vtd[(((long)(bb2 * 16 + hh) << 6) + dd) * 1024 + ii] = pkv;
            }
        }
    } else {
        #pragma unroll
        for (int m = 0; m < 4; m++) {
            #pragma unroll
            for (int r = 0; r < 4; r++) {
                long mm = m0 + wr * 64 + m * 16 + g * 4 + r;
                #pragma unroll
                for (int n = 0; n < 2; n++) {
                    int nn = n0 + wc * 32 + n * 16 + c;
                    outf[mm * 1024 + nn] = acc[m][n][r];
                }
            }
        }
    }
}

// ---------------- K4: flash attention, KVBLK=64, pipelined (dbuf + prefetch) --
// (byte-exact round 11 — proven best ~39 us, VGPR 88)
#define LOADT(KA, KB, BV, JT) do {                                             \
    int _j0 = (JT) * 64;                                                       \
    _Pragma("unroll")                                                          \
    for (int _s = 0; _s < 4; _s++) {                                           \
        const unsigned short* _kr = Kp + (long)(_j0 + _s * 16 + c) * 64 + g * 8; \
        KA[_s] = *(const short8*)(_kr);                                        \
        KB[_s] = *(const short8*)(_kr + 32);                                   \
    }                                                                          \
    const unsigned short* _bp = Bt + ((JT) << 10) + lane * 16;                 \
    BV[0] = *(const short8*)(_bp);                                             \
    BV[1] = *(const short8*)(_bp + 8);                                         \
} while (0)

#define BODY(KA, KB, BV, JT, POFS) do {                                        \
    int _j0 = (JT) * 64;                                                       \
    f32x4 _s[4];                                                               \
    _Pragma("unroll")                                                          \
    for (int _jj = 0; _jj < 4; _jj++) {                                        \
        _s[_jj] = __builtin_amdgcn_mfma_f32_16x16x32_bf16(q0, KA[_jj], zero, 0, 0, 0); \
        _s[_jj] = __builtin_amdgcn_mfma_f32_16x16x32_bf16(q1, KB[_jj], _s[_jj], 0, 0, 0); \
    }                                                                          \
    short8 _v0[4], _v1[4];                                                     \
    _Pragma("unroll")                                                          \
    for (int _dd = 0; _dd < 4; _dd++) {                                        \
        const unsigned short* _vb = Vp + (long)(_dd * 16 + c) * 1024 + _j0 + g * 8; \
        _v0[_dd] = *(const short8*)(_vb);                                      \
        _v1[_dd] = *(const short8*)(_vb + 32);                                 \
    }                                                                          \
    _Pragma("unroll")                                                          \
    for (int _r = 0; _r < 4; _r++) {                                           \
        _Pragma("unroll")                                                      \
        for (int _jj = 0; _jj < 4; _jj++) {                                    \
            int _idx = _r * 4 + _jj;                                           \
            float _bb = (_idx < 8) ? bf2f((unsigned short)BV[0][_idx])         \
                                   : bf2f((unsigned short)BV[1][_idx - 8]);    \
            _s[_jj][_r] += _bb;                                                \
        }                                                                      \
    }                                                                          \
    if ((JT) == nj - 1) {                                                      \
        _Pragma("unroll")                                                      \
        for (int _r = 0; _r < 4; _r++) {                                       \
            int _i = i0 + g * 4 + _r;                                          \
            _Pragma("unroll")                                                  \
            for (int _jj = 0; _jj < 4; _jj++)                                  \
                if (_j0 + _jj * 16 + c > _i) _s[_jj][_r] = -1e9f;              \
        }                                                                      \
    }                                                                          \
    unsigned short* _p = (unsigned short*)(wbase + (POFS));                    \
    _Pragma("unroll")                                                          \
    for (int _r = 0; _r < 4; _r++) {                                           \
        _Pragma("unroll")                                                      \
        for (int _jj = 0; _jj < 4; _jj++) {                                    \
            float _pv = exp2f(__builtin_fmaf(_s[_jj][_r], LOG2E, -8.0f * LOG2E)); \
            l[_r] += _pv;                                                      \
            union { float f; unsigned int u; } _pu; _pu.f = _pv;               \
            _p[(g * 4 + _r) * 72 + c + 16 * _jj] = (unsigned short)(_pu.u >> 16); \
        }                                                                      \
    }                                                                          \
    short8 _pa0 = *(const short8*)&_p[c * 72 + g * 8];                         \
    short8 _pa1 = *(const short8*)&_p[c * 72 + 32 + g * 8];                    \
    _Pragma("unroll")                                                          \
    for (int _dd = 0; _dd < 4; _dd++) {                                        \
        o[_dd] = __builtin_amdgcn_mfma_f32_16x16x32_bf16(_pa0, _v0[_dd], o[_dd], 0, 0, 0); \
        o[_dd] = __builtin_amdgcn_mfma_f32_16x16x32_bf16(_pa1, _v1[_dd], o[_dd], 0, 0, 0); \
    }                                                                          \
} while (0)

__global__ __launch_bounds__(256) void k_attn(
    const unsigned short* __restrict__ Qs, const unsigned short* __restrict__ Ks,
    const unsigned short* __restrict__ VTs, const unsigned short* __restrict__ biasg,
    unsigned short* __restrict__ Os) {
    __shared__ char smem[4 * 5632];
    int bid = blockIdx.x;
    int it = 63 - (bid >> 5);          // heavy stripes dispatched first
    int bh = bid & 31;
    int b = bh >> 4, h = bh & 15;
    int w = threadIdx.x >> 6;
    int lane = threadIdx.x & 63;
    int g = lane >> 4, c = lane & 15;
    int i0 = it * 16;

    char* wbase = smem + w * 5632;

    long plane = ((long)bh) << 16;
    const unsigned short* Qp = Qs + plane;
    const unsigned short* Kp = Ks + plane;
    const unsigned short* Vp = VTs + plane;             // [64 d][1024 j]
    const unsigned short* Bt = biasg + (((long)bh * 64 + it) << 14);

    short8 q0 = *(const short8*)(Qp + (long)(i0 + c) * 64 + g * 8);
    short8 q1 = *(const short8*)(Qp + (long)(i0 + c) * 64 + 32 + g * 8);

    f32x4 zero = {0.f, 0.f, 0.f, 0.f};
    f32x4 o[4]; o[0] = zero; o[1] = zero; o[2] = zero; o[3] = zero;
    float l[4] = {0.f, 0.f, 0.f, 0.f};

    int nj = (it >> 2) + 1;            // 64-col tiles
    short8 kaA[4], kbA[4], bvA[2];
    short8 kaB[4], kbB[4], bvB[2];
    if (w < nj) LOADT(kaA, kbA, bvA, w);
    for (int jt = w; jt < nj; jt += 8) {
        if (jt + 4 < nj) LOADT(kaB, kbB, bvB, jt + 4);
        BODY(kaA, kbA, bvA, jt, 0);
        if (jt + 4 < nj) {
            if (jt + 8 < nj) LOADT(kaA, kbA, bvA, jt + 8);
            BODY(kaB, kbB, bvB, jt + 4, 2304);
        }
    }
    // ---- cross-wave combine: plain sums; all 4 waves participate ----
    float* oc = (float*)wbase;                 // [64][17]
    float* lc = (float*)(wbase + 4352);        // [64][5]
    #pragma unroll
    for (int dd = 0; dd < 4; dd++)
        #pragma unroll
        for (int r = 0; r < 4; r++)
            oc[lane * 17 + dd * 4 + r] = o[dd][r];
    #pragma unroll
    for (int r = 0; r < 4; r++) lc[lane * 5 + r] = l[r];
    __syncthreads();

    {
        int r = w;                              // wave w handles residue r=w
        float lv = 0.f;
        #pragma unroll
        for (int ww = 0; ww < 4; ww++)
            lv += ((const float*)(smem + ww * 5632 + 4352))[lane * 5 + r];
        lv += __shfl_xor(lv, 1); lv += __shfl_xor(lv, 2);
        lv += __shfl_xor(lv, 4); lv += __shfl_xor(lv, 8);
        float linv = 1.0f / lv;
        int i = i0 + g * 4 + r;
        unsigned short* op = Os + ((long)(b * 1024 + i)) * 1024 + h * 64;
        #pragma unroll
        for (int dd = 0; dd < 4; dd++) {
            float ov = 0.f;
            #pragma unroll
            for (int ww = 0; ww < 4; ww++)
                ov += ((const float*)(smem + ww * 5632))[lane * 17 + dd * 4 + r];
            op[dd * 16 + c] = f2bf(ov * linv);
        }
    }
}

// ------------------------------- launch ---------------------------------------
extern "C" void kernel_launch(void* const* d_in, const int* in_sizes, int n_in,
                              void* d_out, int out_size, void* d_ws, size_t ws_size,
                              hipStream_t stream) {
    const float* x     = (const float*)d_in[0];
    const float* Wq    = (const float*)d_in[1];
    const float* Wk    = (const float*)d_in[2];
    const float* Wv    = (const float*)d_in[3];
    const float* Wo    = (const float*)d_in[4];
    const float* Eidx  = (const float*)d_in[5];
    const float* Ebar  = (const float*)d_in[6];
    const float* Epos  = (const float*)d_in[7];
    const float* Eoct  = (const float*)d_in[8];
    const float* Esemi = (const float*)d_in[9];
    const int* barm    = (const int*)d_in[10];
    const int* posm    = (const int*)d_in[11];
    const int* octm    = (const int*)d_in[12];
    const int* semim   = (const int*)d_in[13];
    float* outf = (float*)d_out;

    unsigned short* w = (unsigned short*)d_ws;
    unsigned short* XB   = w;                   // 2M el
    unsigned short* WQB  = w + 2097152;         // 1M el each
    unsigned short* WKB  = w + 3145728;
    unsigned short* WVB  = w + 4194304;
    unsigned short* WOB  = w + 5242880;
    unsigned short* QS   = w + 6291456;         // (b,h,n,d)
    unsigned short* KS   = w + 8388608;
    unsigned short* VTS  = w + 10485760;        // (b,h,d,n)
    unsigned short* OS   = w + 12582912;        // (b,n,h*d)
    unsigned short* BIAS = w + 14680064;        // 32M el, fragment tiles

    k_prep<<<7232, 256, 0, stream>>>(x, Wq, Wk, Wv, Wo, w,
                                     Eidx, Ebar, Epos, Eoct, Esemi,
                                     barm, posm, octm, semim, BIAS);
    k_gemm<<<dim3(16, 16, 3), 256, 0, stream>>>(XB, WQB, WKB, WVB,
                                                QS, KS, VTS, nullptr, -1);
    k_attn<<<2048, 256, 0, stream>>>(QS, KS, VTS, BIAS, OS);
    k_gemm<<<dim3(16, 16, 1), 256, 0, stream>>>(OS, WOB, WOB, WOB,
                                                QS, KS, VTS, outf, 3);
}

// Round 15
// 103.820 us; speedup vs baseline: 1.2140x; 1.0140x over previous
//
#include <hip/hip_runtime.h>
#include <cstdint>
#include <math.h>

typedef __attribute__((ext_vector_type(8))) short short8;
typedef __attribute__((ext_vector_type(4))) float f32x4;

#define LOG2E 1.44269504088896340736f

static __device__ __forceinline__ float bf2f(unsigned short u) {
    union { unsigned int i; float f; } v; v.i = ((unsigned int)u) << 16; return v.f;
}
static __device__ __forceinline__ unsigned short f2bf(float f) {
    union { float f; unsigned int i; } v; v.f = f;
    unsigned int r = v.i + 0x7FFF + ((v.i >> 16) & 1);
    return (unsigned short)(r >> 16);
}

// ---------------- K1: fused prep = bias(1088 blocks first) + convert(6144) ----
// Bias frag layout now SWAPPED-QK C-layout: tile(b,h,ti,tj) base + lane*16 +
// sub*4 + rr holds bias(row i0+(lane&15), col j0 + sub*16 + (lane>>4)*4 + rr).
__global__ __launch_bounds__(256) void k_prep(
    const float* __restrict__ x, const float* __restrict__ wq,
    const float* __restrict__ wk, const float* __restrict__ wv,
    const float* __restrict__ wo, unsigned short* __restrict__ dstconv,
    const float* __restrict__ Eidx, const float* __restrict__ Ebar,
    const float* __restrict__ Epos, const float* __restrict__ Eoct,
    const float* __restrict__ Esemi,
    const int* __restrict__ barm, const int* __restrict__ posm,
    const int* __restrict__ octm, const int* __restrict__ semim,
    unsigned short* __restrict__ biasg) {
    __shared__ float2 t2[8 * 233];
    __shared__ int    pk[16 * 65];

    if (blockIdx.x >= 1088) {
        long t = (long)(blockIdx.x - 1088) * 256 + threadIdx.x;
        long base = t * 4;
        const long NX = 2097152, NW = 1048576;
        const float* src; long off;
        if (base < NX)            { src = x;  off = base; }
        else if (base < NX + NW)  { src = wq; off = base - NX; }
        else if (base < NX + 2*NW){ src = wk; off = base - NX - NW; }
        else if (base < NX + 3*NW){ src = wv; off = base - NX - 2*NW; }
        else                      { src = wo; off = base - NX - 3*NW; }
        float4 v = *(const float4*)(src + off);
        ushort4 o;
        o.x = f2bf(v.x); o.y = f2bf(v.y); o.z = f2bf(v.z); o.w = f2bf(v.w);
        *(ushort4*)(dstconv + base) = o;
        return;
    }
    int fid = blockIdx.x;
    int b = (fid >= 544) ? 1 : 0;
    int f = fid - b * 544;
    int ti, tj;
    if (f >= 480) { int rr = f - 480; ti = 60 + (rr >> 4); tj = rr & 15; }
    else {
        int g = (int)(0.5f * (sqrtf(1.0f + 2.0f * (float)f) - 1.0f));
        while (2 * (g + 1) * (g + 2) <= f) g++;
        while (2 * g * (g + 1) > f) g--;
        int rr = f - 2 * g * (g + 1);
        int q = rr / (g + 1);
        ti = g * 4 + q;
        tj = rr - q * (g + 1);
    }
    int i0 = ti * 16, j0 = tj * 64;

    int t = threadIdx.x;
    int rel_lo = i0 - j0 - 63; if (rel_lo < 0) rel_lo = 0;

    for (int idx = t; idx < 231 * 8; idx += 256) {
        int s = idx >> 3, h2 = idx & 7;
        float va, vb;
        if (s < 80) {
            int src = rel_lo + s; if (src > 1023) src = 1023;
            va = Eidx[src * 16 + h2]; vb = Eidx[src * 16 + h2 + 8];
        } else if (s < 97)  { va = Ebar[(s - 80) * 16 + h2];  vb = Ebar[(s - 80) * 16 + h2 + 8]; }
        else if (s < 193)   { va = Epos[(s - 97) * 16 + h2];  vb = Epos[(s - 97) * 16 + h2 + 8]; }
        else if (s < 218)   { va = Eoct[(s - 193) * 16 + h2]; vb = Eoct[(s - 193) * 16 + h2 + 8]; }
        else                { va = Esemi[(s - 218) * 16 + h2]; vb = Esemi[(s - 218) * 16 + h2 + 8]; }
        t2[h2 * 233 + s] = make_float2(va, vb);
    }
    #pragma unroll
    for (int cc = 0; cc < 4; cc++) {
        int cell = t + cc * 256;
        int i = i0 + (cell >> 6), j = j0 + (cell & 63);
        long ij = ((long)b << 20) + ((long)i << 10) + j;
        int v = (barm[ij] + 1) | ((posm[ij] + 1) << 5) |
                ((octm[ij] + 1) << 12) | ((semim[ij] + 1) << 17);
        pk[(cell >> 6) * 65 + (cell & 63)] = v;
    }
    __syncthreads();

    // epilogue: thread -> (lane = q + 16G, hq); 4 h-streams {hq,hq+4,hq+8,hq+12}
    int lane = t & 63, q = t & 15, G = (t >> 4) & 3, hq = t >> 6;
    int base_rel = (i0 + q) - j0 - rel_lo;
    const float2* TA = &t2[hq * 233];          // pair (hq, hq+8)
    const float2* TB = &t2[(hq + 4) * 233];    // pair (hq+4, hq+12)
    long tbase = ((((long)(b * 16) * 64 + ti) * 16 + tj) << 10) + lane * 16;
    #pragma unroll
    for (int sub = 0; sub < 4; sub++) {
        ushort4 o0, o1, o2, o3;
        #pragma unroll
        for (int rr = 0; rr < 4; rr++) {
            int key = sub * 16 + G * 4 + rr;
            int p = pk[q * 65 + key];
            int sr = base_rel - key; if (sr < 0) sr = 0;
            float2 a0 = TA[sr];
            float2 a1 = TA[80  + (p & 31)];
            float2 a2 = TA[97  + ((p >> 5)  & 127)];
            float2 a3 = TA[193 + ((p >> 12) & 31)];
            float2 a4 = TA[218 + ((p >> 17) & 15)];
            float2 b0 = TB[sr];
            float2 b1 = TB[80  + (p & 31)];
            float2 b2 = TB[97  + ((p >> 5)  & 127)];
            float2 b3 = TB[193 + ((p >> 12) & 31)];
            float2 b4 = TB[218 + ((p >> 17) & 15)];
            float xA = a0.x + a1.x + a2.x + a3.x + a4.x;   // h = hq
            float yA = a0.y + a1.y + a2.y + a3.y + a4.y;   // h = hq+8
            float xB = b0.x + b1.x + b2.x + b3.x + b4.x;   // h = hq+4
            float yB = b0.y + b1.y + b2.y + b3.y + b4.y;   // h = hq+12
            ((unsigned short*)&o0)[rr] = f2bf(xA * 0.125f);
            ((unsigned short*)&o1)[rr] = f2bf(xB * 0.125f);
            ((unsigned short*)&o2)[rr] = f2bf(yA * 0.125f);
            ((unsigned short*)&o3)[rr] = f2bf(yB * 0.125f);
        }
        *(ushort4*)(biasg + tbase + ((long)hq        << 20) + sub * 4) = o0;
        *(ushort4*)(biasg + tbase + ((long)(hq + 4)  << 20) + sub * 4) = o1;
        *(ushort4*)(biasg + tbase + ((long)(hq + 8)  << 20) + sub * 4) = o2;
        *(ushort4*)(biasg + tbase + ((long)(hq + 12) << 20) + sub * 4) = o3;
    }
}

// ---------------- K3/K5: bf16 GEMM, 128x64 tile, global_load_lds --------------
// (unchanged from round 13/14 — validated)
__global__ __launch_bounds__(256) void k_gemm(
    const unsigned short* __restrict__ A,
    const unsigned short* __restrict__ B0, const unsigned short* __restrict__ B1,
    const unsigned short* __restrict__ B2,
    unsigned short* __restrict__ qd, unsigned short* __restrict__ kd,
    unsigned short* __restrict__ vtd, float* __restrict__ outf, int mode) {
    __shared__ unsigned short As[128 * 64];
    __shared__ unsigned short Bs[64 * 64];
    int md = (mode < 0) ? (int)blockIdx.z : mode;
    const unsigned short* B = (md == 1) ? B1 : (md == 2) ? B2 : B0;
    int m0 = blockIdx.x * 128, n0 = blockIdx.y * 64;
    int t = threadIdx.x;
    int w = t >> 6, lane = t & 63, g = lane >> 4, c = lane & 15;
    int wr = w >> 1, wc = w & 1;
    const int K = 1024;
    f32x4 zero = {0.f, 0.f, 0.f, 0.f};
    f32x4 acc[4][2];
    #pragma unroll
    for (int m = 0; m < 4; m++)
        #pragma unroll
        for (int n = 0; n < 2; n++) acc[m][n] = zero;

    int srow = w * 8 + (lane >> 3);
    int scol = (lane & 7) * 8;
    for (int k0 = 0; k0 < K; k0 += 64) {
        __syncthreads();
        #pragma unroll
        for (int qq = 0; qq < 4; qq++) {
            int row = qq * 32 + srow;
            __builtin_amdgcn_global_load_lds(
                (const __attribute__((address_space(1))) unsigned int*)(A + (long)(m0 + row) * K + k0 + scol),
                (__attribute__((address_space(3))) unsigned int*)&As[(qq * 32 + w * 8) * 64],
                16, 0, 0);
        }
        #pragma unroll
        for (int qq = 0; qq < 2; qq++) {
            int row = qq * 32 + srow;
            __builtin_amdgcn_global_load_lds(
                (const __attribute__((address_space(1))) unsigned int*)(B + (long)(n0 + row) * K + k0 + scol),
                (__attribute__((address_space(3))) unsigned int*)&Bs[(qq * 32 + w * 8) * 64],
                16, 0, 0);
        }
        __syncthreads();
        #pragma unroll
        for (int kk = 0; kk < 2; kk++) {
            short8 a[4], bb[2];
            #pragma unroll
            for (int m = 0; m < 4; m++)
                a[m] = *(const short8*)&As[(wr * 64 + m * 16 + c) * 64 + kk * 32 + g * 8];
            #pragma unroll
            for (int n = 0; n < 2; n++)
                bb[n] = *(const short8*)&Bs[(wc * 32 + n * 16 + c) * 64 + kk * 32 + g * 8];
            #pragma unroll
            for (int m = 0; m < 4; m++)
                #pragma unroll
                for (int n = 0; n < 2; n++)
                    acc[m][n] = __builtin_amdgcn_mfma_f32_16x16x32_bf16(a[m], bb[n], acc[m][n], 0, 0, 0);
        }
    }

    if (md <= 1) {
        unsigned short* dst = (md == 0) ? qd : kd;
        float scale = (md == 0) ? 0.125f : 1.0f;
        #pragma unroll
        for (int m = 0; m < 4; m++) {
            #pragma unroll
            for (int r = 0; r < 4; r++) {
                int mm = m0 + wr * 64 + m * 16 + g * 4 + r;
                int bb2 = mm >> 10, ii = mm & 1023;
                #pragma unroll
                for (int n = 0; n < 2; n++) {
                    int nn = n0 + wc * 32 + n * 16 + c;
                    int hh = nn >> 6, dd = nn & 63;
                    dst[(((long)(bb2 * 16 + hh) << 10) + ii) * 64 + dd] = f2bf(acc[m][n][r] * scale);
                }
            }
        }
    } else if (md == 2) {
        #pragma unroll
        for (int m = 0; m < 4; m++) {
            int mm0 = m0 + wr * 64 + m * 16 + g * 4;
            int bb2 = mm0 >> 10, ii = mm0 & 1023;
            #pragma unroll
            for (int n = 0; n < 2; n++) {
                int nn = n0 + wc * 32 + n * 16 + c;
                int hh = nn >> 6, dd = nn & 63;
                ushort4 pkv;
                pkv.x = f2bf(acc[m][n][0]); pkv.y = f2bf(acc[m][n][1]);
                pkv.z = f2bf(acc[m][n][2]); pkv.w = f2bf(acc[m][n][3]);
                *(ushort4*)&vtd[(((long)(bb2 * 16 + hh) << 6) + dd) * 1024 + ii] = pkv;
            }
        }
    } else {
        #pragma unroll
        for (int m = 0; m < 4; m++) {
            #pragma unroll
            for (int r = 0; r < 4; r++) {
                long mm = m0 + wr * 64 + m * 16 + g * 4 + r;
                #pragma unroll
                for (int n = 0; n < 2; n++) {
                    int nn = n0 + wc * 32 + n * 16 + c;
                    outf[mm * 1024 + nn] = acc[m][n][r];
                }
            }
        }
    }
}

// ---------------- K4: flash attention, swapped-QK, LDS-free P-exchange --------
// s = mfma(K,Q): lane owns q = i0+c; s[sub][r] = S[key=sub*16+g*4+r][q].
// P packed via v_cvt_pk_bf16_f32, exchanged across 16-lane groups with shfl,
// consumed as PV B-operand: O^T = mfma(V^T, P). No p_lds. K/V/Q/bias loads
// byte-identical to round 11; prefetch A/B skeleton kept.
#define LOADT(KA, KB, BV, JT) do {                                             \
    int _j0 = (JT) * 64;                                                       \
    _Pragma("unroll")                                                          \
    for (int _s = 0; _s < 4; _s++) {                                           \
        const unsigned short* _kr = Kp + (long)(_j0 + _s * 16 + c) * 64 + g * 8; \
        KA[_s] = *(const short8*)(_kr);                                        \
        KB[_s] = *(const short8*)(_kr + 32);                                   \
    }                                                                          \
    const unsigned short* _bp = Bt + ((JT) << 10) + lane * 16;                 \
    BV[0] = *(const short8*)(_bp);                                             \
    BV[1] = *(const short8*)(_bp + 8);                                         \
} while (0)

#define BODY(KA, KB, BV, JT) do {                                             \
    int _j0 = (JT) * 64;                                                      \
    f32x4 _s[4];                                                              \
    _Pragma("unroll")                                                         \
    for (int _sub = 0; _sub < 4; _sub++) {                                    \
        _s[_sub] = __builtin_amdgcn_mfma_f32_16x16x32_bf16(KA[_sub], q0, zero, 0, 0, 0); \
        _s[_sub] = __builtin_amdgcn_mfma_f32_16x16x32_bf16(KB[_sub], q1, _s[_sub], 0, 0, 0); \
    }                                                                         \
    short8 _v0[4], _v1[4];                                                    \
    _Pragma("unroll")                                                         \
    for (int _dd = 0; _dd < 4; _dd++) {                                       \
        const unsigned short* _vb = Vp + (long)(_dd * 16 + c) * 1024 + _j0 + g * 8; \
        _v0[_dd] = *(const short8*)(_vb);                                     \
        _v1[_dd] = *(const short8*)(_vb + 32);                                \
    }                                                                         \
    unsigned int _P0[4], _P1[4];                                              \
    _Pragma("unroll")                                                         \
    for (int _sub = 0; _sub < 4; _sub++) {                                    \
        float _pe[4];                                                         \
        _Pragma("unroll")                                                     \
        for (int _r = 0; _r < 4; _r++) {                                      \
            int _idx = _sub * 4 + _r;                                         \
            float _ss = _s[_sub][_r] +                                        \
                ((_idx < 8) ? bf2f((unsigned short)BV[0][_idx])               \
                            : bf2f((unsigned short)BV[1][_idx - 8]));         \
            if ((JT) == nj - 1 && _j0 + _sub * 16 + g * 4 + _r > i0 + c)      \
                _ss = -1e9f;                                                  \
            _pe[_r] = exp2f(__builtin_fmaf(_ss, LOG2E, -8.0f * LOG2E));       \
            l += _pe[_r];                                                     \
        }                                                                     \
        asm("v_cvt_pk_bf16_f32 %0, %1, %2" : "=v"(_P0[_sub]) : "v"(_pe[0]), "v"(_pe[1])); \
        asm("v_cvt_pk_bf16_f32 %0, %1, %2" : "=v"(_P1[_sub]) : "v"(_pe[2]), "v"(_pe[3])); \
    }                                                                         \
    _Pragma("unroll")                                                         \
    for (int _ch = 0; _ch < 2; _ch++) {                                       \
        unsigned int _a0 = (unsigned int)__shfl((int)_P0[_ch * 2],     srcA); \
        unsigned int _a1 = (unsigned int)__shfl((int)_P0[_ch * 2 + 1], srcA); \
        unsigned int _b0 = (unsigned int)__shfl((int)_P1[_ch * 2],     srcA); \
        unsigned int _b1 = (unsigned int)__shfl((int)_P1[_ch * 2 + 1], srcA); \
        unsigned int _c0 = (unsigned int)__shfl((int)_P0[_ch * 2],     srcB); \
        unsigned int _c1 = (unsigned int)__shfl((int)_P0[_ch * 2 + 1], srcB); \
        unsigned int _d0 = (unsigned int)__shfl((int)_P1[_ch * 2],     srcB); \
        unsigned int _d1 = (unsigned int)__shfl((int)_P1[_ch * 2 + 1], srcB); \
        union { unsigned int u[4]; short8 s8; } _pb;                          \
        _pb.u[0] = sel ? _a1 : _a0;                                           \
        _pb.u[1] = sel ? _b1 : _b0;                                           \
        _pb.u[2] = sel ? _c1 : _c0;                                           \
        _pb.u[3] = sel ? _d1 : _d0;                                           \
        _Pragma("unroll")                                                     \
        for (int _dd = 0; _dd < 4; _dd++)                                     \
            o[_dd] = __builtin_amdgcn_mfma_f32_16x16x32_bf16(                 \
                (_ch == 0) ? _v0[_dd] : _v1[_dd], _pb.s8, o[_dd], 0, 0, 0);   \
    }                                                                         \
} while (0)

__global__ __launch_bounds__(256) void k_attn(
    const unsigned short* __restrict__ Qs, const unsigned short* __restrict__ Ks,
    const unsigned short* __restrict__ VTs, const unsigned short* __restrict__ biasg,
    unsigned short* __restrict__ Os) {
    // per-wave 4672B: oc 64x17 f32 [0,4352) + lc 64 f32 [4352,4608) + pad
    __shared__ char smem[4 * 4672];
    int bid = blockIdx.x;
    int it = 63 - (bid >> 5);          // heavy stripes dispatched first
    int bh = bid & 31;
    int b = bh >> 4, h = bh & 15;
    int w = threadIdx.x >> 6;
    int lane = threadIdx.x & 63;
    int g = lane >> 4, c = lane & 15;
    int i0 = it * 16;
    int srcA = ((lane >> 4) & 1) * 32 + c;   // P-exchange sources
    int srcB = srcA + 16;
    int sel  = (lane >> 5) & 1;

    char* wbase = smem + w * 4672;

    long plane = ((long)bh) << 16;
    const unsigned short* Qp = Qs + plane;
    const unsigned short* Kp = Ks + plane;
    const unsigned short* Vp = VTs + plane;             // [64 d][1024 j]
    const unsigned short* Bt = biasg + (((long)bh * 64 + it) << 14);

    short8 q0 = *(const short8*)(Qp + (long)(i0 + c) * 64 + g * 8);
    short8 q1 = *(const short8*)(Qp + (long)(i0 + c) * 64 + 32 + g * 8);

    f32x4 zero = {0.f, 0.f, 0.f, 0.f};
    f32x4 o[4]; o[0] = zero; o[1] = zero; o[2] = zero; o[3] = zero;
    float l = 0.f;

    int nj = (it >> 2) + 1;            // 64-col tiles
    short8 kaA[4], kbA[4], bvA[2];
    short8 kaB[4], kbB[4], bvB[2];
    if (w < nj) LOADT(kaA, kbA, bvA, w);
    for (int jt = w; jt < nj; jt += 8) {
        if (jt + 4 < nj) LOADT(kaB, kbB, bvB, jt + 4);
        BODY(kaA, kbA, bvA, jt);
        if (jt + 4 < nj) {
            if (jt + 8 < nj) LOADT(kaA, kbA, bvA, jt + 8);
            BODY(kaB, kbB, bvB, jt + 4);
        }
    }
    // ---- cross-wave combine: plain sums ----
    float* oc = (float*)wbase;                 // [64][17]
    float* lc = (float*)(wbase + 4352);        // [64]
    #pragma unroll
    for (int db = 0; db < 4; db++)
        #pragma unroll
        for (int r = 0; r < 4; r++)
            oc[lane * 17 + db * 4 + r] = o[db][r];
    lc[lane] = l;
    __syncthreads();

    {
        int db = w;                             // wave w stores d-block w
        float lv = 0.f;
        #pragma unroll
        for (int ww = 0; ww < 4; ww++)
            lv += ((const float*)(smem + ww * 4672 + 4352))[lane];
        lv += __shfl_xor(lv, 16);
        lv += __shfl_xor(lv, 32);
        float linv = 1.0f / lv;
        float ov[4];
        #pragma unroll
        for (int r = 0; r < 4; r++) {
            float s = 0.f;
            #pragma unroll
            for (int ww = 0; ww < 4; ww++)
                s += ((const float*)(smem + ww * 4672))[lane * 17 + db * 4 + r];
            ov[r] = s;
        }
        int i = i0 + c;
        unsigned short* op = Os + ((long)(b * 1024 + i)) * 1024 + h * 64 + db * 16 + g * 4;
        ushort4 o4;
        o4.x = f2bf(ov[0] * linv); o4.y = f2bf(ov[1] * linv);
        o4.z = f2bf(ov[2] * linv); o4.w = f2bf(ov[3] * linv);
        *(ushort4*)op = o4;
    }
}

// ------------------------------- launch ---------------------------------------
extern "C" void kernel_launch(void* const* d_in, const int* in_sizes, int n_in,
                              void* d_out, int out_size, void* d_ws, size_t ws_size,
                              hipStream_t stream) {
    const float* x     = (const float*)d_in[0];
    const float* Wq    = (const float*)d_in[1];
    const float* Wk    = (const float*)d_in[2];
    const float* Wv    = (const float*)d_in[3];
    const float* Wo    = (const float*)d_in[4];
    const float* Eidx  = (const float*)d_in[5];
    const float* Ebar  = (const float*)d_in[6];
    const float* Epos  = (const float*)d_in[7];
    const float* Eoct  = (const float*)d_in[8];
    const float* Esemi = (const float*)d_in[9];
    const int* barm    = (const int*)d_in[10];
    const int* posm    = (const int*)d_in[11];
    const int* octm    = (const int*)d_in[12];
    const int* semim   = (const int*)d_in[13];
    float* outf = (float*)d_out;

    unsigned short* w = (unsigned short*)d_ws;
    unsigned short* XB   = w;                   // 2M el
    unsigned short* WQB  = w + 2097152;         // 1M el each
    unsigned short* WKB  = w + 3145728;
    unsigned short* WVB  = w + 4194304;
    unsigned short* WOB  = w + 5242880;
    unsigned short* QS   = w + 6291456;         // (b,h,n,d)
    unsigned short* KS   = w + 8388608;
    unsigned short* VTS  = w + 10485760;        // (b,h,d,n)
    unsigned short* OS   = w + 12582912;        // (b,n,h*d)
    unsigned short* BIAS = w + 14680064;        // 32M el, swapped frag tiles

    k_prep<<<7232, 256, 0, stream>>>(x, Wq, Wk, Wv, Wo, w,
                                     Eidx, Ebar, Epos, Eoct, Esemi,
                                     barm, posm, octm, semim, BIAS);
    k_gemm<<<dim3(16, 16, 3), 256, 0, stream>>>(XB, WQB, WKB, WVB,
                                                QS, KS, VTS, nullptr, -1);
    k_attn<<<2048, 256, 0, stream>>>(QS, KS, VTS, BIAS, OS);
    k_gemm<<<dim3(16, 16, 1), 256, 0, stream>>>(OS, WOB, WOB, WOB,
                                                QS, KS, VTS, outf, 3);
}